// Round 8
// baseline (187.175 us; speedup 1.0000x reference)
//
#include <hip/hip_runtime.h>

// Problem constants
#define S_LEN 512
#define BATCH 16
#define DMODEL 512
#define NHEAD 8
#define DH 64
#define NI 16      // loop count = x.shape[1] = 16 channel iterations

typedef float f32x4 __attribute__((ext_vector_type(4)));
typedef float f32x2 __attribute__((ext_vector_type(2)));
typedef short s16x8 __attribute__((ext_vector_type(8)));

__device__ __forceinline__ unsigned short f2bf(float f){
  unsigned int u = __float_as_uint(f);
  u += 0x7FFFu + ((u >> 16) & 1u);   // RNE
  return (unsigned short)(u >> 16);
}

// async global->LDS 16B copy; lds ptr wave-uniform (HW adds lane*16)
__device__ __forceinline__ void async16(const unsigned short* g, unsigned short* l){
  __builtin_amdgcn_global_load_lds(
      (const __attribute__((address_space(1))) unsigned int*)g,
      (__attribute__((address_space(3))) unsigned int*)l, 16, 0, 0);
}

// x + dpp_permuted(x): VALU-pipe butterfly level (within 16-lane DPP rows)
template<int CTRL>
__device__ __forceinline__ float dppAdd(float x){
  int v = __builtin_amdgcn_update_dpp(0, __float_as_int(x), CTRL, 0xF, 0xF, true);
  return x + __int_as_float(v);
}

// VALU-pipe cross-lane swaps (gfx950): A<->B half/quarter exchange
__device__ __forceinline__ void plswap32(float &a, float &b){
  asm("v_permlane32_swap_b32 %0, %1" : "+v"(a), "+v"(b));
}
__device__ __forceinline__ void plswap16(float &a, float &b){
  asm("v_permlane16_swap_b32 %0, %1" : "+v"(a), "+v"(b));
}
// packed f32x2 -> 2xbf16 in one u32 (RNE)
__device__ __forceinline__ unsigned int cvtpk_bf16(float lo, float hi){
  unsigned int r;
  asm("v_cvt_pk_bf16_f32 %0, %1, %2" : "=v"(r) : "v"(lo), "v"(hi));
  return r;
}

// ---------------- prep: x -> xb (bf16) fused with zcol[b][i][t] = x[t][b][i] ----------------
__global__ void k_prep(const float* __restrict__ x, unsigned short* __restrict__ xb,
                       float* __restrict__ zcol){
  int tid = blockIdx.x * 256 + threadIdx.x;          // 1M threads, 4 elems each
  float4 v = reinterpret_cast<const float4*>(x)[tid];
  ushort4 o;
  o.x = f2bf(v.x); o.y = f2bf(v.y); o.z = f2bf(v.z); o.w = f2bf(v.w);
  reinterpret_cast<ushort4*>(xb)[tid] = o;
  int d0 = (tid & 127) * 4;
  if (d0 < 16){
    int row = tid >> 7;            // t*16 + b
    int t = row >> 4, b = row & 15;
    zcol[(size_t)(b * 16 + d0 + 0) * 512 + t] = v.x;
    zcol[(size_t)(b * 16 + d0 + 1) * 512 + t] = v.y;
    zcol[(size_t)(b * 16 + d0 + 2) * 512 + t] = v.z;
    zcol[(size_t)(b * 16 + d0 + 3) * 512 + t] = v.w;
  }
}

// ---------------- weight cvt: W_in, W_out -> bf16 ----------------
__global__ void k_wcvt(const float* __restrict__ Win, const float* __restrict__ Wout,
                       unsigned short* __restrict__ Winb, unsigned short* __restrict__ Wob){
  int bidx = blockIdx.x;
  if (bidx < 768){
    int t = bidx * 256 + threadIdx.x;
    float4 v = reinterpret_cast<const float4*>(Win)[t];
    ushort4 o;
    o.x = f2bf(v.x); o.y = f2bf(v.y); o.z = f2bf(v.z); o.w = f2bf(v.w);
    reinterpret_cast<ushort4*>(Winb)[t] = o;
  } else {
    int t = (bidx - 768) * 256 + threadIdx.x;
    float4 v = reinterpret_cast<const float4*>(Wout)[t];
    ushort4 o;
    o.x = f2bf(v.x); o.y = f2bf(v.y); o.z = f2bf(v.z); o.w = f2bf(v.w);
    reinterpret_cast<ushort4*>(Wob)[t] = o;
  }
}

// ---------------- K/V projection, 128x128 tile, global_load_lds dbuf ----------------
__global__ __launch_bounds__(256) void k_kv2(const unsigned short* __restrict__ xb,
    const unsigned short* __restrict__ Winb, const float* __restrict__ b_in,
    float* __restrict__ Kf, unsigned short* __restrict__ Vfb){
  __shared__ unsigned short As[2][128 * 32];
  __shared__ unsigned short Bs[2][128 * 32];
  int tid = threadIdx.x;
  int w = tid >> 6, l = tid & 63;
  int ln = l & 15, kb = l >> 4;
  int wr = w >> 1, wc = w & 1;
  int m0 = blockIdx.x * 128;
  int n0 = blockIdx.y * 128;
  const unsigned short* Brow = Winb + (size_t)512 * DMODEL;

  f32x4 acc[4][4];
  #pragma unroll
  for (int mi = 0; mi < 4; ++mi)
    #pragma unroll
    for (int nj = 0; nj < 4; ++nj) acc[mi][nj] = (f32x4){0.f,0.f,0.f,0.f};

  int c0 = tid, c1 = 256 + tid;
  int r0 = c0 >> 2, q0 = c0 & 3, r1 = c1 >> 2, q1 = c1 & 3;
  int lb0 = (w * 64) * 8, lb1 = (256 + w * 64) * 8;

  #define STAGE_KV(kt, buf) do { int k0 = (kt) * 32;                                   \
    async16(xb   + (size_t)(m0 + r0) * DMODEL + k0 + q0 * 8, &As[buf][lb0]);           \
    async16(xb   + (size_t)(m0 + r1) * DMODEL + k0 + q1 * 8, &As[buf][lb1]);           \
    async16(Brow + (size_t)(n0 + r0) * DMODEL + k0 + q0 * 8, &Bs[buf][lb0]);           \
    async16(Brow + (size_t)(n0 + r1) * DMODEL + k0 + q1 * 8, &Bs[buf][lb1]);           \
  } while(0)

  STAGE_KV(0, 0);
  __syncthreads();
  int cur = 0;
  for (int kt = 0; kt < 16; ++kt){
    if (kt < 15) STAGE_KV(kt + 1, cur ^ 1);
    const unsigned short* Ab = &As[cur][(wr * 64 + ln) * 32 + kb * 8];
    const unsigned short* Bb = &Bs[cur][(wc * 64 + ln) * 32 + kb * 8];
    s16x8 af[4], bf[4];
    #pragma unroll
    for (int mi = 0; mi < 4; ++mi) af[mi] = *reinterpret_cast<const s16x8*>(Ab + mi * 16 * 32);
    #pragma unroll
    for (int nj = 0; nj < 4; ++nj) bf[nj] = *reinterpret_cast<const s16x8*>(Bb + nj * 16 * 32);
    #pragma unroll
    for (int mi = 0; mi < 4; ++mi)
      #pragma unroll
      for (int nj = 0; nj < 4; ++nj)
        acc[mi][nj] = __builtin_amdgcn_mfma_f32_16x16x32_bf16(af[mi], bf[nj], acc[mi][nj], 0, 0, 0);
    __syncthreads();
    cur ^= 1;
  }
  #undef STAGE_KV

  #pragma unroll
  for (int nj = 0; nj < 4; ++nj){
    int n = n0 + wc * 64 + nj * 16 + ln;
    float bias = b_in[512 + n];
    #pragma unroll
    for (int mi = 0; mi < 4; ++mi){
      #pragma unroll
      for (int r = 0; r < 4; ++r){
        int m = m0 + wr * 64 + mi * 16 + kb * 4 + r;
        float v = acc[mi][nj][r] + bias;
        if (n < DMODEL) Kf[(size_t)m * DMODEL + n] = v;
        else            Vfb[(size_t)m * DMODEL + (n - DMODEL)] = f2bf(v);
      }
    }
  }
}

// ---------------- transpose Vfb [t*B+b][d] -> VfT [b][d][t] (bf16) ----------------
__global__ void k_tr(const unsigned short* __restrict__ Vfb, unsigned short* __restrict__ VfT){
  __shared__ unsigned short tile[32][34];
  int b = blockIdx.z; int t0 = blockIdx.x * 32; int d0 = blockIdx.y * 32;
  int tx = threadIdx.x & 31, ty = threadIdx.x >> 5;   // 32 x 8
  #pragma unroll
  for (int k = 0; k < 4; ++k){
    int row = ty + 8 * k;
    tile[row][tx] = Vfb[(size_t)((t0 + row) * BATCH + b) * DMODEL + d0 + tx];
  }
  __syncthreads();
  #pragma unroll
  for (int k = 0; k < 4; ++k){
    int row = ty + 8 * k;
    VfT[(size_t)b * (DMODEL * S_LEN) + (size_t)(d0 + row) * S_LEN + t0 + tx] = tile[tx][row];
  }
}

// ---------------- G,H precompute (scaled by 1/8 * log2(e)); t-split over 2 blocks ----------------
__global__ __launch_bounds__(256) void k_gh(const float* __restrict__ W_in,
    const float* __restrict__ b_in, const float* __restrict__ Kf,
    const float* __restrict__ zcol, float* __restrict__ G, float* __restrict__ H){
  const float SCALE = 0.18033688011112042f;   // 0.125 * log2(e)
  int bh = blockIdx.x >> 1, th = blockIdx.x & 1;
  int b = bh >> 3, h = bh & 7;
  __shared__ float u[64][17];     // u[d][i] = Wq[h*64+d][i]
  __shared__ float cvec[64];      // bq[hslice]
  __shared__ float alpha[16], beta[16];
  int tid = threadIdx.x;
  for (int idx = tid; idx < 1024; idx += 256){
    int d = idx >> 4, i = idx & 15;
    u[d][i] = W_in[(size_t)(h * 64 + d) * DMODEL + i];
  }
  if (tid < 64) cvec[tid] = b_in[h * 64 + tid];
  __syncthreads();
  if (tid < 16){
    float a = 0.f, be = 0.f;
    for (int d = 0; d < 64; ++d){
      float wk = W_in[(size_t)(512 + h * 64 + d) * DMODEL + tid];
      a  += u[d][tid] * wk;
      be += cvec[d] * wk;
    }
    alpha[tid] = a; beta[tid] = be;
  }
  __syncthreads();
  int t = th * 256 + tid;  // 0..511 across 2 blocks
  float K[64];
  const float* kp = Kf + (size_t)(t * BATCH + b) * DMODEL + h * 64;
  #pragma unroll
  for (int d = 0; d < 64; d += 4){
    float4 v = *reinterpret_cast<const float4*>(kp + d);
    K[d] = v.x; K[d+1] = v.y; K[d+2] = v.z; K[d+3] = v.w;
  }
  float Bt = 0.f;
  #pragma unroll
  for (int d = 0; d < 64; ++d) Bt += cvec[d] * K[d];
  for (int i = 0; i < 16; ++i){
    float A = 0.f;
    #pragma unroll
    for (int d = 0; d < 64; ++d) A += u[d][i] * K[d];
    float z = zcol[(size_t)(b * 16 + i) * 512 + t];
    G[(size_t)(bh * 16 + i) * 512 + t] = (A  - alpha[i] * z) * SCALE;
    H[(size_t)(bh * 16 + i) * 512 + t] = (Bt - beta[i]  * z) * SCALE;
  }
}

// ---------------- fused softmax + PV: one block = (bh, 32 s-rows), 8 waves ----------------
// blockIdx swizzled so all 16 blocks of a bh land on XCD bh%8 (L2 locality for G/H/z/VfT).
// G/H/z rows LDS-staged via global_load_lds (double-buffered, waves 0-5 issue, 1 barrier/i).
__global__ __launch_bounds__(512) void k_smpv(const float* __restrict__ G,
    const float* __restrict__ H, const float* __restrict__ zcol,
    const unsigned short* __restrict__ VfT, const float* __restrict__ W_in,
    unsigned short* __restrict__ Ob){
  __shared__ unsigned short Pl[32 * 512];   // [s][t] bf16, byte-XOR-swizzled (bits 4-6)
  __shared__ float Rs[32][17];
  __shared__ float Wvl[64][17];
  __shared__ float GHZ[2][3][512];          // staged g/h/z rows (dbuf)
  int j = blockIdx.x;
  int xcd = j & 7, rest = j >> 3;
  int bh_hi = rest & 15, sb = rest >> 4;     // sb in [0,16)
  int bh = bh_hi * 8 + xcd;                  // j%8 == bh%8 -> same XCD per bh
  int b = bh >> 3, h = bh & 7;
  int tid = threadIdx.x, w = tid >> 6, l = tid & 63;

  for (int idx = tid; idx < 1024; idx += 512){   // Wv slice: [64 d][16 i]
    int d = idx >> 4, i = idx & 15;
    Wvl[d][i] = W_in[(size_t)(2 * DMODEL + h * 64 + d) * DMODEL + i];
  }

  const float* gb = G    + ((size_t)bh * NI) * S_LEN;
  const float* hb = H    + ((size_t)bh * NI) * S_LEN;
  const float* zb = zcol + ((size_t)b  * NI) * S_LEN;
  int t0 = l * 4, t1 = 256 + l * 4;   // this lane's t ownership (2 x 4 contiguous)
  int s_w = sb * 32 + w * 4;          // this wave's 4 s-rows (global s)

  // staging params (waves 0-5: arr 0=g,1=h,2=z; half 0/1)
  int arr = w >> 1, half = w & 1;
  const float* sbase = (arr == 0 ? gb : (arr == 1 ? hb : zb)) + half * 256;

  f32x2 Pacc[4][4];
  #pragma unroll
  for (int r = 0; r < 4; ++r)
    #pragma unroll
    for (int jp = 0; jp < 4; ++jp) Pacc[r][jp] = (f32x2){0.f, 0.f};

  // prologue: stage i=0 into buf 0
  if (w < 6)
    async16((const unsigned short*)sbase + (size_t)l * 8,
            (unsigned short*)&GHZ[0][arr][half * 256]);
  __syncthreads();

  for (int i = 0; i < NI; ++i){
    int cb = i & 1;
    if (i + 1 < NI && w < 6)
      async16((const unsigned short*)(sbase + ((i + 1) << 9)) + (size_t)l * 8,
              (unsigned short*)&GHZ[cb ^ 1][arr][half * 256]);

    const float* Gl = &GHZ[cb][0][0];
    const float* Hl = &GHZ[cb][1][0];
    const float* Zl = &GHZ[cb][2][0];
    f32x4 gA = *reinterpret_cast<const f32x4*>(Gl + t0);
    f32x4 gB = *reinterpret_cast<const f32x4*>(Gl + t1);
    f32x4 hA = *reinterpret_cast<const f32x4*>(Hl + t0);
    f32x4 hB = *reinterpret_cast<const f32x4*>(Hl + t1);
    f32x4 zA = *reinterpret_cast<const f32x4*>(Zl + t0);
    f32x4 zB = *reinterpret_cast<const f32x4*>(Zl + t1);
    float4 y4 = *reinterpret_cast<const float4*>(Zl + s_w);   // wave-uniform broadcast
    f32x2 g2[4] = {gA.lo, gA.hi, gB.lo, gB.hi};
    f32x2 h2[4] = {hA.lo, hA.hi, hB.lo, hB.hi};
    f32x2 z2[4] = {zA.lo, zA.hi, zB.lo, zB.hi};
    float ys[4] = {y4.x, y4.y, y4.z, y4.w};

    f32x2 E[4][4];
    float pd[4], pr[4];
    #pragma unroll
    for (int r = 0; r < 4; ++r){
      f32x2 yv = {ys[r], ys[r]};
      f32x2 dacc = {0.f, 0.f}, racc = {0.f, 0.f};
      #pragma unroll
      for (int jp = 0; jp < 4; ++jp){
        f32x2 a = yv * g2[jp] + h2[jp];
        f32x2 e;
        e.x = __builtin_amdgcn_exp2f(a.x);
        e.y = __builtin_amdgcn_exp2f(a.y);
        E[r][jp] = e;
        dacc += e;
        racc += e * z2[jp];
      }
      pd[r] = dacc.x + dacc.y;
      pr[r] = racc.x + racc.y;
    }

    // fold 4 rows onto 16-lane groups: permlane swaps (VALU), then DPP butterfly
    plswap32(pd[0], pd[2]);  float dq0 = pd[0] + pd[2];
    plswap32(pd[1], pd[3]);  float dq1 = pd[1] + pd[3];
    plswap32(pr[0], pr[2]);  float rq0 = pr[0] + pr[2];
    plswap32(pr[1], pr[3]);  float rq1 = pr[1] + pr[3];
    plswap16(dq0, dq1);      float du = dq0 + dq1;   // group g holds row (w*4+g) partial
    plswap16(rq0, rq1);      float ru = rq0 + rq1;
    du = dppAdd<0x140>(du); ru = dppAdd<0x140>(ru);   // row_mirror
    du = dppAdd<0x141>(du); ru = dppAdd<0x141>(ru);   // row_half_mirror
    du = dppAdd<0x4E>(du);  ru = dppAdd<0x4E>(ru);    // quad_perm xor2
    du = dppAdd<0xB1>(du);  ru = dppAdd<0xB1>(ru);    // quad_perm xor1
    float inv = __builtin_amdgcn_rcpf(du);
    if ((l & 15) == 0)
      Rs[w * 4 + (l >> 4)][i] = ru * inv;
    #pragma unroll
    for (int r = 0; r < 4; ++r){
      float ir = __int_as_float(__builtin_amdgcn_readlane(__float_as_int(inv), 16 * r));
      f32x2 iv = {ir, ir};
      #pragma unroll
      for (int jp = 0; jp < 4; ++jp) Pacc[r][jp] += E[r][jp] * iv;
    }
    __syncthreads();   // stage(i+1) landed; all reads of buf cb done before i+1 overwrites cb^1... (dbuf swap)
  }

  // write Pbar to swizzled LDS (bf16, packed via v_cvt_pk_bf16_f32)
  #pragma unroll
  for (int r = 0; r < 4; ++r){
    int sl = w * 4 + r;
    unsigned int u0 = cvtpk_bf16(Pacc[r][0].x, Pacc[r][0].y);
    unsigned int u1 = cvtpk_bf16(Pacc[r][1].x, Pacc[r][1].y);
    unsigned int u2 = cvtpk_bf16(Pacc[r][2].x, Pacc[r][2].y);
    unsigned int u3 = cvtpk_bf16(Pacc[r][3].x, Pacc[r][3].y);
    int xr = (sl & 7) << 4;
    char* rowp = (char*)Pl + sl * 1024;
    uint2 v01; v01.x = u0; v01.y = u1;
    uint2 v23; v23.x = u2; v23.y = u3;
    *reinterpret_cast<uint2*>(rowp + ((l * 8) ^ xr)) = v01;
    *reinterpret_cast<uint2*>(rowp + ((512 + l * 8) ^ xr)) = v23;
  }
  __syncthreads();

  // phase 2: 8 waves, each a 16s x 16d tile over K=512
  int ln = l & 15, kb = l >> 4;
  int sh = (w & 1) * 16;        // s-half
  int dt = (w >> 1) * 16;       // d-tile
  const unsigned short* bp = VfT + (size_t)b * (DMODEL * S_LEN)
                             + (size_t)(h * 64 + dt + ln) * S_LEN + kb * 8;
  char* arow = (char*)Pl + (sh + ln) * 1024;
  int xa = (ln & 7) << 4;
  f32x4 acc = {0.f, 0.f, 0.f, 0.f};
  #pragma unroll
  for (int kt = 0; kt < 16; ++kt){
    s16x8 af = *reinterpret_cast<const s16x8*>(arow + ((kt * 64 + kb * 16) ^ xa));
    s16x8 bf = *reinterpret_cast<const s16x8*>(bp + kt * 32);
    acc = __builtin_amdgcn_mfma_f32_16x16x32_bf16(af, bf, acc, 0, 0, 0);
  }
  #pragma unroll
  for (int r = 0; r < 4; ++r){
    int sl = sh + kb * 4 + r;
    float corr = 0.f;
    #pragma unroll
    for (int i = 0; i < 16; ++i) corr += Rs[sl][i] * Wvl[dt + ln][i];
    float v = acc[r] - corr;
    int m = sb * 32 + sl;
    Ob[(size_t)(m * BATCH + b) * DMODEL + h * 64 + dt + ln] = f2bf(v);
  }
}

// ---------------- out-proj: out = Ob @ W_out^T + 16*b_out, 128x128 tile ----------------
__global__ __launch_bounds__(256) void k_out2(const unsigned short* __restrict__ Ob,
    const unsigned short* __restrict__ Wob, const float* __restrict__ b_out,
    float* __restrict__ out){
  __shared__ unsigned short As[2][128 * 32];
  __shared__ unsigned short Bs[2][128 * 32];
  int tid = threadIdx.x;
  int w = tid >> 6, l = tid & 63;
  int ln = l & 15, kb = l >> 4;
  int wr = w >> 1, wc = w & 1;
  int m0 = blockIdx.x * 128;
  int n0 = blockIdx.y * 128;

  f32x4 acc[4][4];
  #pragma unroll
  for (int mi = 0; mi < 4; ++mi)
    #pragma unroll
    for (int nj = 0; nj < 4; ++nj) acc[mi][nj] = (f32x4){0.f,0.f,0.f,0.f};

  int c0 = tid, c1 = 256 + tid;
  int r0 = c0 >> 2, q0 = c0 & 3, r1 = c1 >> 2, q1 = c1 & 3;
  int lb0 = (w * 64) * 8, lb1 = (256 + w * 64) * 8;

  #define STAGE_O(kt, buf) do { int k0 = (kt) * 32;                                    \
    async16(Ob  + (size_t)(m0 + r0) * DMODEL + k0 + q0 * 8, &As[buf][lb0]);            \
    async16(Ob  + (size_t)(m0 + r1) * DMODEL + k0 + q1 * 8, &As[buf][lb1]);            \
    async16(Wob + (size_t)(n0 + r0) * DMODEL + k0 + q0 * 8, &Bs[buf][lb0]);            \
    async16(Wob + (size_t)(n0 + r1) * DMODEL + k0 + q1 * 8, &Bs[buf][lb1]);            \
  } while(0)

  STAGE_O(0, 0);
  __syncthreads();
  int cur = 0;
  for (int kt = 0; kt < 16; ++kt){
    if (kt < 15) STAGE_O(kt + 1, cur ^ 1);
    const unsigned short* Ab = &As[cur][(wr * 64 + ln) * 32 + kb * 8];
    const unsigned short* Bb = &Bs[cur][(wc * 64 + ln) * 32 + kb * 8];
    s16x8 af[4], bf[4];
    #pragma unroll
    for (int mi = 0; mi < 4; ++mi) af[mi] = *reinterpret_cast<const s16x8*>(Ab + mi * 16 * 32);
    #pragma unroll
    for (int nj = 0; nj < 4; ++nj) bf[nj] = *reinterpret_cast<const s16x8*>(Bb + nj * 16 * 32);
    #pragma unroll
    for (int mi = 0; mi < 4; ++mi)
      #pragma unroll
      for (int nj = 0; nj < 4; ++nj)
        acc[mi][nj] = __builtin_amdgcn_mfma_f32_16x16x32_bf16(af[mi], bf[nj], acc[mi][nj], 0, 0, 0);
    __syncthreads();
    cur ^= 1;
  }
  #undef STAGE_O

  #pragma unroll
  for (int nj = 0; nj < 4; ++nj){
    int n = n0 + wc * 64 + nj * 16 + ln;
    float bias = 16.0f * b_out[n];
    #pragma unroll
    for (int mi = 0; mi < 4; ++mi){
      #pragma unroll
      for (int r = 0; r < 4; ++r){
        int m = m0 + wr * 64 + mi * 16 + kb * 4 + r;
        out[(size_t)m * DMODEL + n] = acc[mi][nj][r] + bias;
      }
    }
  }
}

extern "C" void kernel_launch(void* const* d_in, const int* in_sizes, int n_in,
                              void* d_out, int out_size, void* d_ws, size_t ws_size,
                              hipStream_t stream) {
  const float* x     = (const float*)d_in[0];
  const float* W_in  = (const float*)d_in[1];
  const float* b_in  = (const float*)d_in[2];
  const float* W_out = (const float*)d_in[3];
  const float* b_out = (const float*)d_in[4];
  float* out = (float*)d_out;

  size_t off = 0;
  char* base = (char*)d_ws;
  auto alloc = [&](size_t bytes) -> void* {
    void* p = base + off;
    off += (bytes + 255) & ~(size_t)255;
    return p;
  };
  unsigned short* xb   = (unsigned short*)alloc(8388608);    // x bf16
  unsigned short* Winb = (unsigned short*)alloc(1572864);    // W_in bf16
  unsigned short* Wob  = (unsigned short*)alloc(524288);     // W_out bf16
  float*          zcol = (float*)alloc(524288);              // [b][i][t]
  float*          Kf   = (float*)alloc(16777216);            // [r][d] f32
  unsigned short* Vfb  = (unsigned short*)alloc(8388608);    // [r][d] bf16
  unsigned short* VfT  = (unsigned short*)alloc(8388608);    // [b][d][t] bf16
  float*          G    = (float*)alloc(4194304);             // [bh][i][t] (x log2e/8)
  float*          H    = (float*)alloc(4194304);             // [bh][i][t] (x log2e/8)
  unsigned short* Ob   = (unsigned short*)alloc(8388608);    // [r][d] bf16

  k_prep<<<4096, 256, 0, stream>>>(x, xb, zcol);
  k_wcvt<<<1024, 256, 0, stream>>>(W_in, W_out, Winb, Wob);

  { dim3 g(64, 8); k_kv2<<<g, 256, 0, stream>>>(xb, Winb, b_in, Kf, Vfb); }
  { dim3 g(16, 16, 16); k_tr<<<g, 256, 0, stream>>>(Vfb, VfT); }
  k_gh<<<256, 256, 0, stream>>>(W_in, b_in, Kf, zcol, G, H);

  k_smpv<<<2048, 512, 0, stream>>>(G, H, zcol, VfT, W_in, Ob);

  { dim3 g(64, 4); k_out2<<<g, 256, 0, stream>>>(Ob, Wob, b_out, out); }
}

// Round 9
// 181.141 us; speedup vs baseline: 1.0333x; 1.0333x over previous
//
#include <hip/hip_runtime.h>

// Problem constants
#define S_LEN 512
#define BATCH 16
#define DMODEL 512
#define NHEAD 8
#define DH 64
#define NI 16      // loop count = x.shape[1] = 16 channel iterations

typedef float f32x4 __attribute__((ext_vector_type(4)));
typedef float f32x2 __attribute__((ext_vector_type(2)));
typedef short s16x8 __attribute__((ext_vector_type(8)));

__device__ __forceinline__ unsigned short f2bf(float f){
  unsigned int u = __float_as_uint(f);
  u += 0x7FFFu + ((u >> 16) & 1u);   // RNE
  return (unsigned short)(u >> 16);
}

// async global->LDS 16B copy; lds ptr wave-uniform (HW adds lane*16)
__device__ __forceinline__ void async16(const unsigned short* g, unsigned short* l){
  __builtin_amdgcn_global_load_lds(
      (const __attribute__((address_space(1))) unsigned int*)g,
      (__attribute__((address_space(3))) unsigned int*)l, 16, 0, 0);
}

// x + dpp_permuted(x): VALU-pipe butterfly level (within 16-lane DPP rows)
template<int CTRL>
__device__ __forceinline__ float dppAdd(float x){
  int v = __builtin_amdgcn_update_dpp(0, __float_as_int(x), CTRL, 0xF, 0xF, true);
  return x + __int_as_float(v);
}

// VALU-pipe cross-lane swaps (gfx950): A<->B half/quarter exchange
__device__ __forceinline__ void plswap32(float &a, float &b){
  asm("v_permlane32_swap_b32 %0, %1" : "+v"(a), "+v"(b));
}
__device__ __forceinline__ void plswap16(float &a, float &b){
  asm("v_permlane16_swap_b32 %0, %1" : "+v"(a), "+v"(b));
}
// packed f32x2 -> 2xbf16 in one u32 (RNE)
__device__ __forceinline__ unsigned int cvtpk_bf16(float lo, float hi){
  unsigned int r;
  asm("v_cvt_pk_bf16_f32 %0, %1, %2" : "=v"(r) : "v"(lo), "v"(hi));
  return r;
}

// ---------------- prep: x -> xb (bf16) fused with zcol[b][i][t] = x[t][b][i] ----------------
__global__ void k_prep(const float* __restrict__ x, unsigned short* __restrict__ xb,
                       float* __restrict__ zcol){
  int tid = blockIdx.x * 256 + threadIdx.x;          // 1M threads, 4 elems each
  float4 v = reinterpret_cast<const float4*>(x)[tid];
  ushort4 o;
  o.x = f2bf(v.x); o.y = f2bf(v.y); o.z = f2bf(v.z); o.w = f2bf(v.w);
  reinterpret_cast<ushort4*>(xb)[tid] = o;
  int d0 = (tid & 127) * 4;
  if (d0 < 16){
    int row = tid >> 7;            // t*16 + b
    int t = row >> 4, b = row & 15;
    zcol[(size_t)(b * 16 + d0 + 0) * 512 + t] = v.x;
    zcol[(size_t)(b * 16 + d0 + 1) * 512 + t] = v.y;
    zcol[(size_t)(b * 16 + d0 + 2) * 512 + t] = v.z;
    zcol[(size_t)(b * 16 + d0 + 3) * 512 + t] = v.w;
  }
}

// ---------------- weight cvt: W_in, W_out -> bf16 ----------------
__global__ void k_wcvt(const float* __restrict__ Win, const float* __restrict__ Wout,
                       unsigned short* __restrict__ Winb, unsigned short* __restrict__ Wob){
  int bidx = blockIdx.x;
  if (bidx < 768){
    int t = bidx * 256 + threadIdx.x;
    float4 v = reinterpret_cast<const float4*>(Win)[t];
    ushort4 o;
    o.x = f2bf(v.x); o.y = f2bf(v.y); o.z = f2bf(v.z); o.w = f2bf(v.w);
    reinterpret_cast<ushort4*>(Winb)[t] = o;
  } else {
    int t = (bidx - 768) * 256 + threadIdx.x;
    float4 v = reinterpret_cast<const float4*>(Wout)[t];
    ushort4 o;
    o.x = f2bf(v.x); o.y = f2bf(v.y); o.z = f2bf(v.z); o.w = f2bf(v.w);
    reinterpret_cast<ushort4*>(Wob)[t] = o;
  }
}

// ---------------- K/V projection, 128x128 tile, global_load_lds dbuf ----------------
__global__ __launch_bounds__(256) void k_kv2(const unsigned short* __restrict__ xb,
    const unsigned short* __restrict__ Winb, const float* __restrict__ b_in,
    float* __restrict__ Kf, unsigned short* __restrict__ Vfb){
  __shared__ unsigned short As[2][128 * 32];
  __shared__ unsigned short Bs[2][128 * 32];
  int tid = threadIdx.x;
  int w = tid >> 6, l = tid & 63;
  int ln = l & 15, kb = l >> 4;
  int wr = w >> 1, wc = w & 1;
  int m0 = blockIdx.x * 128;
  int n0 = blockIdx.y * 128;
  const unsigned short* Brow = Winb + (size_t)512 * DMODEL;

  f32x4 acc[4][4];
  #pragma unroll
  for (int mi = 0; mi < 4; ++mi)
    #pragma unroll
    for (int nj = 0; nj < 4; ++nj) acc[mi][nj] = (f32x4){0.f,0.f,0.f,0.f};

  int c0 = tid, c1 = 256 + tid;
  int r0 = c0 >> 2, q0 = c0 & 3, r1 = c1 >> 2, q1 = c1 & 3;
  int lb0 = (w * 64) * 8, lb1 = (256 + w * 64) * 8;

  #define STAGE_KV(kt, buf) do { int k0 = (kt) * 32;                                   \
    async16(xb   + (size_t)(m0 + r0) * DMODEL + k0 + q0 * 8, &As[buf][lb0]);           \
    async16(xb   + (size_t)(m0 + r1) * DMODEL + k0 + q1 * 8, &As[buf][lb1]);           \
    async16(Brow + (size_t)(n0 + r0) * DMODEL + k0 + q0 * 8, &Bs[buf][lb0]);           \
    async16(Brow + (size_t)(n0 + r1) * DMODEL + k0 + q1 * 8, &Bs[buf][lb1]);           \
  } while(0)

  STAGE_KV(0, 0);
  __syncthreads();
  int cur = 0;
  for (int kt = 0; kt < 16; ++kt){
    if (kt < 15) STAGE_KV(kt + 1, cur ^ 1);
    const unsigned short* Ab = &As[cur][(wr * 64 + ln) * 32 + kb * 8];
    const unsigned short* Bb = &Bs[cur][(wc * 64 + ln) * 32 + kb * 8];
    s16x8 af[4], bf[4];
    #pragma unroll
    for (int mi = 0; mi < 4; ++mi) af[mi] = *reinterpret_cast<const s16x8*>(Ab + mi * 16 * 32);
    #pragma unroll
    for (int nj = 0; nj < 4; ++nj) bf[nj] = *reinterpret_cast<const s16x8*>(Bb + nj * 16 * 32);
    #pragma unroll
    for (int mi = 0; mi < 4; ++mi)
      #pragma unroll
      for (int nj = 0; nj < 4; ++nj)
        acc[mi][nj] = __builtin_amdgcn_mfma_f32_16x16x32_bf16(af[mi], bf[nj], acc[mi][nj], 0, 0, 0);
    __syncthreads();
    cur ^= 1;
  }
  #undef STAGE_KV

  #pragma unroll
  for (int nj = 0; nj < 4; ++nj){
    int n = n0 + wc * 64 + nj * 16 + ln;
    float bias = b_in[512 + n];
    #pragma unroll
    for (int mi = 0; mi < 4; ++mi){
      #pragma unroll
      for (int r = 0; r < 4; ++r){
        int m = m0 + wr * 64 + mi * 16 + kb * 4 + r;
        float v = acc[mi][nj][r] + bias;
        if (n < DMODEL) Kf[(size_t)m * DMODEL + n] = v;
        else            Vfb[(size_t)m * DMODEL + (n - DMODEL)] = f2bf(v);
      }
    }
  }
}

// ---------------- transpose Vfb [t*B+b][d] -> VfT [b][d][t] (bf16) ----------------
__global__ void k_tr(const unsigned short* __restrict__ Vfb, unsigned short* __restrict__ VfT){
  __shared__ unsigned short tile[32][34];
  int b = blockIdx.z; int t0 = blockIdx.x * 32; int d0 = blockIdx.y * 32;
  int tx = threadIdx.x & 31, ty = threadIdx.x >> 5;   // 32 x 8
  #pragma unroll
  for (int k = 0; k < 4; ++k){
    int row = ty + 8 * k;
    tile[row][tx] = Vfb[(size_t)((t0 + row) * BATCH + b) * DMODEL + d0 + tx];
  }
  __syncthreads();
  #pragma unroll
  for (int k = 0; k < 4; ++k){
    int row = ty + 8 * k;
    VfT[(size_t)b * (DMODEL * S_LEN) + (size_t)(d0 + row) * S_LEN + t0 + tx] = tile[tx][row];
  }
}

// ---------------- G,H precompute (scaled by 1/8 * log2(e)); t-split over 2 blocks ----------------
__global__ __launch_bounds__(256) void k_gh(const float* __restrict__ W_in,
    const float* __restrict__ b_in, const float* __restrict__ Kf,
    const float* __restrict__ zcol, float* __restrict__ G, float* __restrict__ H){
  const float SCALE = 0.18033688011112042f;   // 0.125 * log2(e)
  int bh = blockIdx.x >> 1, th = blockIdx.x & 1;
  int b = bh >> 3, h = bh & 7;
  __shared__ float u[64][17];     // u[d][i] = Wq[h*64+d][i]
  __shared__ float cvec[64];      // bq[hslice]
  __shared__ float alpha[16], beta[16];
  int tid = threadIdx.x;
  for (int idx = tid; idx < 1024; idx += 256){
    int d = idx >> 4, i = idx & 15;
    u[d][i] = W_in[(size_t)(h * 64 + d) * DMODEL + i];
  }
  if (tid < 64) cvec[tid] = b_in[h * 64 + tid];
  __syncthreads();
  if (tid < 16){
    float a = 0.f, be = 0.f;
    for (int d = 0; d < 64; ++d){
      float wk = W_in[(size_t)(512 + h * 64 + d) * DMODEL + tid];
      a  += u[d][tid] * wk;
      be += cvec[d] * wk;
    }
    alpha[tid] = a; beta[tid] = be;
  }
  __syncthreads();
  int t = th * 256 + tid;  // 0..511 across 2 blocks
  float K[64];
  const float* kp = Kf + (size_t)(t * BATCH + b) * DMODEL + h * 64;
  #pragma unroll
  for (int d = 0; d < 64; d += 4){
    float4 v = *reinterpret_cast<const float4*>(kp + d);
    K[d] = v.x; K[d+1] = v.y; K[d+2] = v.z; K[d+3] = v.w;
  }
  float Bt = 0.f;
  #pragma unroll
  for (int d = 0; d < 64; ++d) Bt += cvec[d] * K[d];
  for (int i = 0; i < 16; ++i){
    float A = 0.f;
    #pragma unroll
    for (int d = 0; d < 64; ++d) A += u[d][i] * K[d];
    float z = zcol[(size_t)(b * 16 + i) * 512 + t];
    G[(size_t)(bh * 16 + i) * 512 + t] = (A  - alpha[i] * z) * SCALE;
    H[(size_t)(bh * 16 + i) * 512 + t] = (Bt - beta[i]  * z) * SCALE;
  }
}

// ---------------- fused softmax + PV: one block = (bh, 32 s-rows), 8 waves ----------------
// blockIdx swizzled so all 16 blocks of a bh land on XCD bh%8 (L2 locality for G/H/z/VfT).
// launch_bounds(512,2): allow up to 256 VGPR so E[4][4] stays live (no exp remat);
// asm-touch on E forbids rematerialization of the exp2 results.
__global__ __launch_bounds__(512, 2) void k_smpv(const float* __restrict__ G,
    const float* __restrict__ H, const float* __restrict__ zcol,
    const unsigned short* __restrict__ VfT, const float* __restrict__ W_in,
    unsigned short* __restrict__ Ob){
  __shared__ unsigned short Pl[32 * 512];   // [s][t] bf16, byte-XOR-swizzled (bits 4-6)
  __shared__ float Rs[32][17];
  __shared__ float Wvl[64][17];
  int j = blockIdx.x;
  int xcd = j & 7, rest = j >> 3;
  int bh_hi = rest & 15, sb = rest >> 4;     // sb in [0,16)
  int bh = bh_hi * 8 + xcd;                  // j%8 == bh%8 -> same XCD per bh
  int b = bh >> 3, h = bh & 7;
  int tid = threadIdx.x, w = tid >> 6, l = tid & 63;

  for (int idx = tid; idx < 1024; idx += 512){   // Wv slice: [64 d][16 i]
    int d = idx >> 4, i = idx & 15;
    Wvl[d][i] = W_in[(size_t)(2 * DMODEL + h * 64 + d) * DMODEL + i];
  }

  const float* gb = G    + ((size_t)bh * NI) * S_LEN;
  const float* hb = H    + ((size_t)bh * NI) * S_LEN;
  const float* zb = zcol + ((size_t)b  * NI) * S_LEN;
  int t0 = l * 4, t1 = 256 + l * 4;   // this lane's t ownership (2 x 4 contiguous)
  int s_w = sb * 32 + w * 4;          // this wave's 4 s-rows (global s)

  f32x2 Pacc[4][4];
  #pragma unroll
  for (int r = 0; r < 4; ++r)
    #pragma unroll
    for (int jp = 0; jp < 4; ++jp) Pacc[r][jp] = (f32x2){0.f, 0.f};

  for (int i = 0; i < NI; ++i){
    const float* gp = gb + (i << 9);
    const float* hp = hb + (i << 9);
    const float* zp = zb + (i << 9);
    f32x4 gA = *reinterpret_cast<const f32x4*>(gp + t0);
    f32x4 gB = *reinterpret_cast<const f32x4*>(gp + t1);
    f32x4 hA = *reinterpret_cast<const f32x4*>(hp + t0);
    f32x4 hB = *reinterpret_cast<const f32x4*>(hp + t1);
    f32x4 zA = *reinterpret_cast<const f32x4*>(zp + t0);
    f32x4 zB = *reinterpret_cast<const f32x4*>(zp + t1);
    float4 y4 = *reinterpret_cast<const float4*>(zp + s_w);
    f32x2 g2[4] = {gA.lo, gA.hi, gB.lo, gB.hi};
    f32x2 h2[4] = {hA.lo, hA.hi, hB.lo, hB.hi};
    f32x2 z2[4] = {zA.lo, zA.hi, zB.lo, zB.hi};
    float ys[4] = {y4.x, y4.y, y4.z, y4.w};

    f32x2 E[4][4];
    float pd[4], pr[4];
    #pragma unroll
    for (int r = 0; r < 4; ++r){
      f32x2 yv = {ys[r], ys[r]};
      f32x2 dacc = {0.f, 0.f}, racc = {0.f, 0.f};
      #pragma unroll
      for (int jp = 0; jp < 4; ++jp){
        f32x2 a = yv * g2[jp] + h2[jp];
        f32x2 e;
        e.x = __builtin_amdgcn_exp2f(a.x);
        e.y = __builtin_amdgcn_exp2f(a.y);
        asm volatile("" : "+v"(e));     // forbid remat: keep E live in VGPRs
        E[r][jp] = e;
        dacc += e;
        racc += e * z2[jp];
      }
      pd[r] = dacc.x + dacc.y;
      pr[r] = racc.x + racc.y;
    }

    // fold 4 rows onto 16-lane groups: permlane swaps (VALU), then DPP butterfly
    plswap32(pd[0], pd[2]);  float dq0 = pd[0] + pd[2];
    plswap32(pd[1], pd[3]);  float dq1 = pd[1] + pd[3];
    plswap32(pr[0], pr[2]);  float rq0 = pr[0] + pr[2];
    plswap32(pr[1], pr[3]);  float rq1 = pr[1] + pr[3];
    plswap16(dq0, dq1);      float du = dq0 + dq1;   // group g holds row (w*4+g) partial
    plswap16(rq0, rq1);      float ru = rq0 + rq1;
    du = dppAdd<0x140>(du); ru = dppAdd<0x140>(ru);   // row_mirror
    du = dppAdd<0x141>(du); ru = dppAdd<0x141>(ru);   // row_half_mirror
    du = dppAdd<0x4E>(du);  ru = dppAdd<0x4E>(ru);    // quad_perm xor2
    du = dppAdd<0xB1>(du);  ru = dppAdd<0xB1>(ru);    // quad_perm xor1
    float inv = __builtin_amdgcn_rcpf(du);
    if ((l & 15) == 0)
      Rs[w * 4 + (l >> 4)][i] = ru * inv;
    #pragma unroll
    for (int r = 0; r < 4; ++r){
      float ir = __int_as_float(__builtin_amdgcn_readlane(__float_as_int(inv), 16 * r));
      f32x2 iv = {ir, ir};
      #pragma unroll
      for (int jp = 0; jp < 4; ++jp) Pacc[r][jp] += E[r][jp] * iv;
    }
  }

  // write Pbar to swizzled LDS (bf16, packed via v_cvt_pk_bf16_f32)
  #pragma unroll
  for (int r = 0; r < 4; ++r){
    int sl = w * 4 + r;
    unsigned int u0 = cvtpk_bf16(Pacc[r][0].x, Pacc[r][0].y);
    unsigned int u1 = cvtpk_bf16(Pacc[r][1].x, Pacc[r][1].y);
    unsigned int u2 = cvtpk_bf16(Pacc[r][2].x, Pacc[r][2].y);
    unsigned int u3 = cvtpk_bf16(Pacc[r][3].x, Pacc[r][3].y);
    int xr = (sl & 7) << 4;
    char* rowp = (char*)Pl + sl * 1024;
    uint2 v01; v01.x = u0; v01.y = u1;
    uint2 v23; v23.x = u2; v23.y = u3;
    *reinterpret_cast<uint2*>(rowp + ((l * 8) ^ xr)) = v01;
    *reinterpret_cast<uint2*>(rowp + ((512 + l * 8) ^ xr)) = v23;
  }
  __syncthreads();

  // phase 2: 8 waves, each a 16s x 16d tile over K=512
  int ln = l & 15, kb = l >> 4;
  int sh = (w & 1) * 16;        // s-half
  int dt = (w >> 1) * 16;       // d-tile
  const unsigned short* bp = VfT + (size_t)b * (DMODEL * S_LEN)
                             + (size_t)(h * 64 + dt + ln) * S_LEN + kb * 8;
  char* arow = (char*)Pl + (sh + ln) * 1024;
  int xa = (ln & 7) << 4;
  f32x4 acc = {0.f, 0.f, 0.f, 0.f};
  #pragma unroll
  for (int kt = 0; kt < 16; ++kt){
    s16x8 af = *reinterpret_cast<const s16x8*>(arow + ((kt * 64 + kb * 16) ^ xa));
    s16x8 bf = *reinterpret_cast<const s16x8*>(bp + kt * 32);
    acc = __builtin_amdgcn_mfma_f32_16x16x32_bf16(af, bf, acc, 0, 0, 0);
  }
  #pragma unroll
  for (int r = 0; r < 4; ++r){
    int sl = sh + kb * 4 + r;
    float corr = 0.f;
    #pragma unroll
    for (int i = 0; i < 16; ++i) corr += Rs[sl][i] * Wvl[dt + ln][i];
    float v = acc[r] - corr;
    int m = sb * 32 + sl;
    Ob[(size_t)(m * BATCH + b) * DMODEL + h * 64 + dt + ln] = f2bf(v);
  }
}

// ---------------- out-proj: out = Ob @ W_out^T + 16*b_out, 128x128 tile ----------------
__global__ __launch_bounds__(256) void k_out2(const unsigned short* __restrict__ Ob,
    const unsigned short* __restrict__ Wob, const float* __restrict__ b_out,
    float* __restrict__ out){
  __shared__ unsigned short As[2][128 * 32];
  __shared__ unsigned short Bs[2][128 * 32];
  int tid = threadIdx.x;
  int w = tid >> 6, l = tid & 63;
  int ln = l & 15, kb = l >> 4;
  int wr = w >> 1, wc = w & 1;
  int m0 = blockIdx.x * 128;
  int n0 = blockIdx.y * 128;

  f32x4 acc[4][4];
  #pragma unroll
  for (int mi = 0; mi < 4; ++mi)
    #pragma unroll
    for (int nj = 0; nj < 4; ++nj) acc[mi][nj] = (f32x4){0.f,0.f,0.f,0.f};

  int c0 = tid, c1 = 256 + tid;
  int r0 = c0 >> 2, q0 = c0 & 3, r1 = c1 >> 2, q1 = c1 & 3;
  int lb0 = (w * 64) * 8, lb1 = (256 + w * 64) * 8;

  #define STAGE_O(kt, buf) do { int k0 = (kt) * 32;                                    \
    async16(Ob  + (size_t)(m0 + r0) * DMODEL + k0 + q0 * 8, &As[buf][lb0]);            \
    async16(Ob  + (size_t)(m0 + r1) * DMODEL + k0 + q1 * 8, &As[buf][lb1]);            \
    async16(Wob + (size_t)(n0 + r0) * DMODEL + k0 + q0 * 8, &Bs[buf][lb0]);            \
    async16(Wob + (size_t)(n0 + r1) * DMODEL + k0 + q1 * 8, &Bs[buf][lb1]);            \
  } while(0)

  STAGE_O(0, 0);
  __syncthreads();
  int cur = 0;
  for (int kt = 0; kt < 16; ++kt){
    if (kt < 15) STAGE_O(kt + 1, cur ^ 1);
    const unsigned short* Ab = &As[cur][(wr * 64 + ln) * 32 + kb * 8];
    const unsigned short* Bb = &Bs[cur][(wc * 64 + ln) * 32 + kb * 8];
    s16x8 af[4], bf[4];
    #pragma unroll
    for (int mi = 0; mi < 4; ++mi) af[mi] = *reinterpret_cast<const s16x8*>(Ab + mi * 16 * 32);
    #pragma unroll
    for (int nj = 0; nj < 4; ++nj) bf[nj] = *reinterpret_cast<const s16x8*>(Bb + nj * 16 * 32);
    #pragma unroll
    for (int mi = 0; mi < 4; ++mi)
      #pragma unroll
      for (int nj = 0; nj < 4; ++nj)
        acc[mi][nj] = __builtin_amdgcn_mfma_f32_16x16x32_bf16(af[mi], bf[nj], acc[mi][nj], 0, 0, 0);
    __syncthreads();
    cur ^= 1;
  }
  #undef STAGE_O

  #pragma unroll
  for (int nj = 0; nj < 4; ++nj){
    int n = n0 + wc * 64 + nj * 16 + ln;
    float bias = 16.0f * b_out[n];
    #pragma unroll
    for (int mi = 0; mi < 4; ++mi){
      #pragma unroll
      for (int r = 0; r < 4; ++r){
        int m = m0 + wr * 64 + mi * 16 + kb * 4 + r;
        out[(size_t)m * DMODEL + n] = acc[mi][nj][r] + bias;
      }
    }
  }
}

extern "C" void kernel_launch(void* const* d_in, const int* in_sizes, int n_in,
                              void* d_out, int out_size, void* d_ws, size_t ws_size,
                              hipStream_t stream) {
  const float* x     = (const float*)d_in[0];
  const float* W_in  = (const float*)d_in[1];
  const float* b_in  = (const float*)d_in[2];
  const float* W_out = (const float*)d_in[3];
  const float* b_out = (const float*)d_in[4];
  float* out = (float*)d_out;

  size_t off = 0;
  char* base = (char*)d_ws;
  auto alloc = [&](size_t bytes) -> void* {
    void* p = base + off;
    off += (bytes + 255) & ~(size_t)255;
    return p;
  };
  unsigned short* xb   = (unsigned short*)alloc(8388608);    // x bf16
  unsigned short* Winb = (unsigned short*)alloc(1572864);    // W_in bf16
  unsigned short* Wob  = (unsigned short*)alloc(524288);     // W_out bf16
  float*          zcol = (float*)alloc(524288);              // [b][i][t]
  float*          Kf   = (float*)alloc(16777216);            // [r][d] f32
  unsigned short* Vfb  = (unsigned short*)alloc(8388608);    // [r][d] bf16
  unsigned short* VfT  = (unsigned short*)alloc(8388608);    // [b][d][t] bf16
  float*          G    = (float*)alloc(4194304);             // [bh][i][t] (x log2e/8)
  float*          H    = (float*)alloc(4194304);             // [bh][i][t] (x log2e/8)
  unsigned short* Ob   = (unsigned short*)alloc(8388608);    // [r][d] bf16

  k_prep<<<4096, 256, 0, stream>>>(x, xb, zcol);
  k_wcvt<<<1024, 256, 0, stream>>>(W_in, W_out, Winb, Wob);

  { dim3 g(64, 8); k_kv2<<<g, 256, 0, stream>>>(xb, Winb, b_in, Kf, Vfb); }
  { dim3 g(16, 16, 16); k_tr<<<g, 256, 0, stream>>>(Vfb, VfT); }
  k_gh<<<256, 256, 0, stream>>>(W_in, b_in, Kf, zcol, G, H);

  k_smpv<<<2048, 512, 0, stream>>>(G, H, zcol, VfT, W_in, Ob);

  { dim3 g(64, 4); k_out2<<<g, 256, 0, stream>>>(Ob, Wob, b_out, out); }
}